// Round 16
// baseline (424.225 us; speedup 1.0000x reference)
//
#include <hip/hip_runtime.h>
#include <hip/hip_bf16.h>
#include <math.h>

#define GK 2048
#define NCB 16   // query-side partial stride

typedef __attribute__((ext_vector_type(8))) short bf16x8;
typedef __attribute__((ext_vector_type(4))) float f32x4;
typedef __attribute__((ext_vector_type(4))) float f4v;
typedef __attribute__((ext_vector_type(4))) unsigned short u16x4;
typedef __attribute__((ext_vector_type(8))) unsigned short u16x8;

__device__ __forceinline__ unsigned short f2bf(float x) {
    unsigned int u = __float_as_uint(x);
    u += 0x7fffu + ((u >> 16) & 1u);
    return (unsigned short)(u >> 16);
}

__device__ __forceinline__ void gl_lds16(const void* g, void* l) {
    __builtin_amdgcn_global_load_lds(
        (const __attribute__((address_space(1))) unsigned int*)g,
        (__attribute__((address_space(3))) unsigned int*)l, 16, 0, 0);
}

// ---------- per-batch mask compaction: idx[b][j] = l of j-th unmasked, cnt[b] ----------
__global__ void mask_scan_kernel(const int* __restrict__ mask,
                                 int* __restrict__ idx, int* __restrict__ cnt) {
    int b = blockIdx.x, tid = threadIdx.x;
    int wave = tid >> 6, lane = tid & 63;
    __shared__ int wsum[4];
    __shared__ int sbase;
    if (tid == 0) sbase = 0;
    __syncthreads();
    for (int c = 0; c < 8; ++c) {
        int l = (c << 8) + tid;
        int m = mask[(b << 11) + l];
        unsigned long long bal = __ballot(m != 0);
        int wpfx = __popcll(bal & ((1ull << lane) - 1ull));
        if (lane == 0) wsum[wave] = __popcll(bal);
        int rbase = sbase;
        __syncthreads();
        int woff = 0;
#pragma unroll
        for (int w2 = 0; w2 < 4; ++w2) if (w2 < wave) woff += wsum[w2];
        if (m) idx[(b << 11) + rbase + woff + wpfx] = l;
        int tot = wsum[0] + wsum[1] + wsum[2] + wsum[3];
        __syncthreads();
        if (tid == 0) sbase = rbase + tot;
        __syncthreads();
    }
    if (tid == 0) cnt[b] = sbase;
}

// ---------- merged prep: gather-cvt key (compacted), cvt W_t/W_q/q_key, w3, Dq ----------
__global__ void prep_kernel(const float* __restrict__ Wt, const float* __restrict__ Wq,
                            const float* __restrict__ q_key, const float* __restrict__ key,
                            const float* __restrict__ query, const float* __restrict__ b_q,
                            const float* __restrict__ alphas_state,
                            const int* __restrict__ idx, const int* __restrict__ cnt,
                            unsigned short* __restrict__ Wtk, unsigned short* __restrict__ Wqk,
                            unsigned short* __restrict__ qkb, unsigned short* __restrict__ keyb,
                            float* __restrict__ avec_c,
                            float* __restrict__ w3q, float* __restrict__ w3t,
                            float* __restrict__ Dq) {
    int b = blockIdx.x, tid = threadIdx.x;
    if (b < 32768) {                       // compacted key slot: batch bb, slot j
        int bb = b >> 11, j = b & 2047;
        int c_ = cnt[bb];
        int lim = (c_ + 255) & ~255;       // rows beyond tile boundary never read
        if (j >= lim) return;
        unsigned short* drow = keyb + ((long)b << 11);
        if (j < c_) {
            int l = idx[b];
            const float* srow = key + (((size_t)(bb << 11) + l) << 11);
            long i = (long)tid << 3;
            f4v a = *(const f4v*)(srow + i);
            f4v c = *(const f4v*)(srow + i + 4);
            u16x8 r;
            r[0] = f2bf(a[0]); r[1] = f2bf(a[1]); r[2] = f2bf(a[2]); r[3] = f2bf(a[3]);
            r[4] = f2bf(c[0]); r[5] = f2bf(c[1]); r[6] = f2bf(c[2]); r[7] = f2bf(c[3]);
            *(u16x8*)(drow + i) = r;
            if (tid == 0) avec_c[b] = alphas_state[(bb << 11) + l];
        } else {
            u16x8 z = (u16x8)(short)0;
            *(u16x8*)(drow + (tid << 3)) = z;
            if (tid == 0) avec_c[b] = 0.f;
        }
        return;
    }
    int b2 = b - 32768;
    if (b2 < 2048) {
        const float* s = Wt + (size_t)b2 * 5121;
        unsigned short* d = Wtk + (size_t)b2 * 2048;
#pragma unroll
        for (int k = 0; k < 8; k++) { int c = tid + (k << 8); d[c] = f2bf(s[c]); }
    } else if (b2 < 4096) {
        int o = b2 - 2048;
        const float* s = Wq + (size_t)o * 3073;
        unsigned short* d = Wqk + (size_t)o * 2048;
#pragma unroll
        for (int k = 0; k < 8; k++) { int c = tid + (k << 8); d[c] = f2bf(s[c]); }
    } else if (b2 < 5120) {
        long i = ((long)(b2 - 4096) * 256 + tid) * 8;
        f4v a = *(const f4v*)(q_key + i);
        f4v c = *(const f4v*)(q_key + i + 4);
        u16x8 r;
        r[0] = f2bf(a[0]); r[1] = f2bf(a[1]); r[2] = f2bf(a[2]); r[3] = f2bf(a[3]);
        r[4] = f2bf(c[0]); r[5] = f2bf(c[1]); r[6] = f2bf(c[2]); r[7] = f2bf(c[3]);
        *(u16x8*)(qkb + i) = r;
    } else if (b2 < 5128) {
        int o = (b2 - 5120) * 256 + tid;
        w3q[o] = Wq[(size_t)o * 3073 + 3072];
        w3t[o] = Wt[(size_t)o * 5121 + 3072];
    } else {
        // Dq[bb][o] = b_q[o] + sum_i query[bb,i]*Wq[o,2048+i]
        int wave = tid >> 6, lane = tid & 63;
        int o = (b2 - 5128) * 4 + wave;
        const float* wrow = Wq + (size_t)o * 3073 + 2048;
        float acc[16];
#pragma unroll
        for (int z = 0; z < 16; z++) acc[z] = 0.f;
        for (int i = lane; i < 1024; i += 64) {
            float wv = wrow[i];
            const float* qp = query + i;
#pragma unroll
            for (int z = 0; z < 16; z++) acc[z] += wv * qp[z * 1024];
        }
#pragma unroll
        for (int z = 0; z < 16; z++) {
            float v = acc[z];
            for (int off = 1; off < 64; off <<= 1) v += __shfl_xor(v, off);
            if (lane == 0) Dq[(z << 11) + o] = v + b_q[o];
        }
    }
}

// ---------- per-batch constant D[b][o] (text side) ----------
template <int KLEN>
__global__ __launch_bounds__(256) void dconst_kernel(
    const float* __restrict__ W, long ldw,
    const float* __restrict__ bias,
    const float* __restrict__ query,
    const float* __restrict__ qctx,
    float* __restrict__ Dout) {
    int tid = threadIdx.x;
    int wave = tid >> 6, lane = tid & 63;
    int o = blockIdx.x * 4 + wave;
    const float* wrow = W + (size_t)o * ldw + 2048;
    float acc[16];
#pragma unroll
    for (int b2 = 0; b2 < 16; b2++) acc[b2] = 0.f;
    for (int i = lane; i < KLEN; i += 64) {
        if (KLEN == 1024 || i < 1024) {
            float wv = wrow[i];
            const float* qp = query + i;
#pragma unroll
            for (int b2 = 0; b2 < 16; b2++) acc[b2] += wv * qp[b2 * 1024];
        } else {
            float wv = wrow[i + 1];  // skip alphas column at 3072
            const float* cp = qctx + (i - 1024);
#pragma unroll
            for (int b2 = 0; b2 < 16; b2++) acc[b2] += wv * cp[b2 * 2048];
        }
    }
#pragma unroll
    for (int b2 = 0; b2 < 16; b2++) {
        float v = acc[b2];
        for (int off = 1; off < 64; off <<= 1) v += __shfl_xor(v, off);
        if (lane == 0) Dout[(b2 << 11) + o] = v + bias[o];
    }
}

// ---------- query-side fused GEMM (128x128 tile, m97 structure) ----------
template <int LOG_RPB>
__global__ __launch_bounds__(256) void gemm_score(
    const unsigned short* __restrict__ A,
    const unsigned short* __restrict__ Bt,
    const float* __restrict__ Dc,
    const float* __restrict__ avec,
    const float* __restrict__ w3,
    const float* __restrict__ tvec,
    float* __restrict__ partial,
    int row0) {
    __shared__ unsigned short As[128 * 32];
    __shared__ unsigned short Bs[128 * 32];
    __shared__ float red[128][2];

    int nwg = gridDim.x;
    int bid = blockIdx.x;
    int q8 = nwg >> 3;
    int wg = (bid & 7) * q8 + (bid >> 3);
    int rb = wg >> 4, cb = wg & 15;

    int tid = threadIdx.x;
    int wave = tid >> 6, lane = tid & 63;
    int wr = wave >> 1, wc = wave & 1;
    int l15 = lane & 15, lhi = lane >> 4;

    const unsigned short* Ab = A + (size_t)rb * 128 * GK;
    const unsigned short* Bb = Bt + (size_t)cb * 128 * GK;

    int r0 = tid >> 2, c0 = (tid & 3) << 3;

    f32x4 acc[4][4];
#pragma unroll
    for (int i = 0; i < 4; i++)
#pragma unroll
        for (int j = 0; j < 4; j++) acc[i][j] = (f32x4)0.f;

    unsigned short* AsW0 = As + (wave << 9);
    unsigned short* AsW1 = As + 2048 + (wave << 9);
    unsigned short* BsW0 = Bs + (wave << 9);
    unsigned short* BsW1 = Bs + 2048 + (wave << 9);

    for (int k0 = 0; k0 < GK; k0 += 32) {
        __syncthreads();
        gl_lds16(Ab + (size_t)r0 * GK + k0 + c0, AsW0);
        gl_lds16(Ab + (size_t)(r0 + 64) * GK + k0 + c0, AsW1);
        gl_lds16(Bb + (size_t)r0 * GK + k0 + c0, BsW0);
        gl_lds16(Bb + (size_t)(r0 + 64) * GK + k0 + c0, BsW1);
        __syncthreads();
        bf16x8 a[4], b[4];
#pragma unroll
        for (int mi = 0; mi < 4; mi++)
            a[mi] = *(const bf16x8*)(As + (((wr << 6) + (mi << 4) + l15) << 5) + (lhi << 3));
#pragma unroll
        for (int ni = 0; ni < 4; ni++)
            b[ni] = *(const bf16x8*)(Bs + (((wc << 6) + (ni << 4) + l15) << 5) + (lhi << 3));
#pragma unroll
        for (int mi = 0; mi < 4; mi++)
#pragma unroll
            for (int ni = 0; ni < 4; ni++)
                acc[mi][ni] = __builtin_amdgcn_mfma_f32_16x16x32_bf16(a[mi], b[ni], acc[mi][ni], 0, 0, 0);
    }

    int grow_base = row0 + (rb << 7) + (wr << 6);
    int bb = grow_base >> LOG_RPB;
    int gcol = (cb << 7) + (wc << 6) + l15;
    float Dco[4], w3o[4], tv[4];
#pragma unroll
    for (int ni = 0; ni < 4; ni++) {
        int o = gcol + (ni << 4);
        Dco[ni] = Dc[(bb << 11) + o];
        w3o[ni] = w3[o];
        tv[ni] = tvec[o];
    }
#pragma unroll
    for (int mi = 0; mi < 4; mi++) {
#pragma unroll
        for (int j = 0; j < 4; j++) {
            int rloc = (mi << 4) + (lhi << 2) + j;
            float av = avec[grow_base + rloc];
            float s = 0.f;
#pragma unroll
            for (int ni = 0; ni < 4; ni++) {
                float x = acc[mi][ni][j] + Dco[ni] + av * w3o[ni];
                x = fminf(fmaxf(x, -15.f), 15.f);
                float e = __expf(2.f * x);
                s += ((e - 1.f) / (e + 1.f)) * tv[ni];
            }
#pragma unroll
            for (int off = 1; off < 16; off <<= 1) s += __shfl_xor(s, off);
            if (l15 == 0) red[(wr << 6) + rloc][wc] = s;
        }
    }
    __syncthreads();
    if (tid < 128) {
        partial[(size_t)(row0 + (rb << 7) + tid) * NCB + cb] = red[tid][0] + red[tid][1];
    }
}

// ---------- text-side 256x256 8-phase GEMM (r10 structure) + mask-compaction exit ----
#define MFMA16(A, B, C) __builtin_amdgcn_mfma_f32_16x16x32_bf16(A, B, C, 0, 0, 0)

#define STAGE2(GB, GR0, K0, LB) do { \
    int _rr = lane >> 3; \
    int _cc = ((lane & 7) ^ _rr) << 3; \
    gl_lds16((GB) + (size_t)((GR0) + (wid << 3) + _rr) * GK + (K0) + _cc, lds + (LB) + (wid << 9)); \
    gl_lds16((GB) + (size_t)((GR0) + 64 + (wid << 3) + _rr) * GK + (K0) + _cc, lds + (LB) + 4096 + (wid << 9)); \
  } while (0)

#define WAIT4 do { asm volatile("s_waitcnt vmcnt(4)" ::: "memory"); __builtin_amdgcn_sched_barrier(0); } while (0)
#define NOWAIT do { } while (0)

#define PHASE(YOFF, Q, FIRSTB, STAGE_STMT, BOUNDARY) do { \
    bf16x8 a00, a01, a10, a11; \
    if (FIRSTB) { \
        b00 = *(const bf16x8*)(lds8 + bB0[0] + (YOFF)); b01 = *(const bf16x8*)(lds8 + bB1[0] + (YOFF)); \
        b10 = *(const bf16x8*)(lds8 + bB0[1] + (YOFF)); b11 = *(const bf16x8*)(lds8 + bB1[1] + (YOFF)); \
        b20 = *(const bf16x8*)(lds8 + bB0[2] + (YOFF)); b21 = *(const bf16x8*)(lds8 + bB1[2] + (YOFF)); \
        b30 = *(const bf16x8*)(lds8 + bB0[3] + (YOFF)); b31 = *(const bf16x8*)(lds8 + bB1[3] + (YOFF)); \
    } \
    a00 = *(const bf16x8*)(lds8 + aA0[2*(Q)  ] + (YOFF)); a01 = *(const bf16x8*)(lds8 + aA1[2*(Q)  ] + (YOFF)); \
    a10 = *(const bf16x8*)(lds8 + aA0[2*(Q)+1] + (YOFF)); a11 = *(const bf16x8*)(lds8 + aA1[2*(Q)+1] + (YOFF)); \
    STAGE_STMT; \
    BOUNDARY; \
    __builtin_amdgcn_s_barrier(); \
    asm volatile("s_waitcnt lgkmcnt(0)" ::: "memory"); \
    __builtin_amdgcn_sched_barrier(0); \
    __builtin_amdgcn_s_setprio(1); \
    acc[2*(Q)  ][0] = MFMA16(a00, b00, acc[2*(Q)  ][0]); \
    acc[2*(Q)  ][0] = MFMA16(a01, b01, acc[2*(Q)  ][0]); \
    acc[2*(Q)  ][1] = MFMA16(a00, b10, acc[2*(Q)  ][1]); \
    acc[2*(Q)  ][1] = MFMA16(a01, b11, acc[2*(Q)  ][1]); \
    acc[2*(Q)  ][2] = MFMA16(a00, b20, acc[2*(Q)  ][2]); \
    acc[2*(Q)  ][2] = MFMA16(a01, b21, acc[2*(Q)  ][2]); \
    acc[2*(Q)  ][3] = MFMA16(a00, b30, acc[2*(Q)  ][3]); \
    acc[2*(Q)  ][3] = MFMA16(a01, b31, acc[2*(Q)  ][3]); \
    acc[2*(Q)+1][0] = MFMA16(a10, b00, acc[2*(Q)+1][0]); \
    acc[2*(Q)+1][0] = MFMA16(a11, b01, acc[2*(Q)+1][0]); \
    acc[2*(Q)+1][1] = MFMA16(a10, b10, acc[2*(Q)+1][1]); \
    acc[2*(Q)+1][1] = MFMA16(a11, b11, acc[2*(Q)+1][1]); \
    acc[2*(Q)+1][2] = MFMA16(a10, b20, acc[2*(Q)+1][2]); \
    acc[2*(Q)+1][2] = MFMA16(a11, b21, acc[2*(Q)+1][2]); \
    acc[2*(Q)+1][3] = MFMA16(a10, b30, acc[2*(Q)+1][3]); \
    acc[2*(Q)+1][3] = MFMA16(a11, b31, acc[2*(Q)+1][3]); \
    __builtin_amdgcn_s_setprio(0); \
  } while (0)

__global__ __launch_bounds__(512, 2) void gemm256(
    const unsigned short* __restrict__ A,
    const unsigned short* __restrict__ Bt,
    const float* __restrict__ Dc,
    const float* __restrict__ avec,
    const float* __restrict__ w3,
    const float* __restrict__ tvec,
    const int* __restrict__ cnt,
    float* __restrict__ partial) {
    extern __shared__ unsigned short lds[];
    char* lds8 = (char*)lds;
    const int XA = 0, YA = 16384, XB = 32768, YB = 49152;  // ushort units

    int nwg = gridDim.x;
    int bid = blockIdx.x;
    int q8 = nwg >> 3;
    int wg = (bid & 7) * q8 + (bid >> 3);   // bijective XCD swizzle (nwg % 8 == 0)
    int rb = wg >> 3, cb = wg & 7;

    // mask-compaction early exit: this 256-row tile is entirely padding
    if (((rb & 7) << 8) >= cnt[rb >> 3]) return;

    int tid = threadIdx.x;
    int wid = tid >> 6, lane = tid & 63;
    int wr = wid >> 2, wc = wid & 3;
    int l15 = lane & 15, lhi = lane >> 4;

    const unsigned short* Aq = A;
    const unsigned short* Bq = Bt;
    int arow = rb << 8;
    int brow = cb << 8;

    // hoisted LDS read addresses (bytes, X-group base; Y-group = +32768)
    int sw0 = ((lhi ^ (l15 & 7)) << 4);
    int sw1 = (((4 | lhi) ^ (l15 & 7)) << 4);
    int aA0[8], aA1[8], bB0[4], bB1[4];
#pragma unroll
    for (int mi = 0; mi < 8; mi++) {
        int r = (wr << 7) + (mi << 4) + l15;
        aA0[mi] = (r << 7) + sw0;
        aA1[mi] = (r << 7) + sw1;
    }
#pragma unroll
    for (int ni = 0; ni < 4; ni++) {
        int r = (wc << 6) + (ni << 4) + l15;
        bB0[ni] = 65536 + (r << 7) + sw0;
        bB1[ni] = 65536 + (r << 7) + sw1;
    }

    f32x4 acc[8][4];
#pragma unroll
    for (int i = 0; i < 8; i++)
#pragma unroll
        for (int j = 0; j < 4; j++) acc[i][j] = (f32x4)0.f;

    bf16x8 b00, b01, b10, b11, b20, b21, b30, b31;

    // prologue: X <- tile0 (B then A), Y.B <- tile1
    STAGE2(Bq, brow, 0, XB);
    STAGE2(Bq, brow + 128, 0, XB + 8192);
    STAGE2(Aq, arow, 0, XA);
    STAGE2(Aq, arow + 128, 0, XA + 8192);
    STAGE2(Bq, brow, 64, YB);
    STAGE2(Bq, brow + 128, 64, YB + 8192);
    asm volatile("s_waitcnt vmcnt(4)" ::: "memory");
    __builtin_amdgcn_sched_barrier(0);
    __builtin_amdgcn_s_barrier();

    for (int it = 0; it < 16; ++it) {
        int k1 = ((it << 1) + 1) << 6;           // tile 2i+1 A (real)
        int k2 = (((it << 1) + 2) << 6) & 2047;  // tile 2i+2 (masked harmless on last iter)
        int k3 = (((it << 1) + 3) << 6) & 2047;  // tile 2i+3
        PHASE(0,     0, 1, STAGE2(Aq, arow,       k1, YA),        NOWAIT);
        PHASE(0,     1, 0, STAGE2(Aq, arow + 128, k1, YA + 8192), NOWAIT);
        PHASE(0,     2, 0, STAGE2(Bq, brow,       k2, XB),        NOWAIT);
        PHASE(0,     3, 0, STAGE2(Bq, brow + 128, k2, XB + 8192), WAIT4);
        PHASE(32768, 0, 1, STAGE2(Aq, arow,       k2, XA),        NOWAIT);
        PHASE(32768, 1, 0, STAGE2(Aq, arow + 128, k2, XA + 8192), NOWAIT);
        PHASE(32768, 2, 0, STAGE2(Bq, brow,       k3, YB),        NOWAIT);
        PHASE(32768, 3, 0, STAGE2(Bq, brow + 128, k3, YB + 8192), WAIT4);
    }

    // epilogue: fused tanh-dot partial scores (compacted rows)
    int gcolb = (cb << 8) + (wc << 6) + l15;
    int bb = rb >> 3;
    float Dco[4], w3o[4], tv[4];
#pragma unroll
    for (int ni = 0; ni < 4; ++ni) {
        int o = gcolb + (ni << 4);
        Dco[ni] = Dc[(bb << 11) + o];
        w3o[ni] = w3[o];
        tv[ni] = tvec[o];
    }
    float* red = (float*)(lds + 65536);  // [256][4]
#pragma unroll
    for (int mi = 0; mi < 8; ++mi) {
#pragma unroll
        for (int j = 0; j < 4; ++j) {
            int rloc = (wr << 7) + (mi << 4) + (lhi << 2) + j;
            float av = avec[(rb << 8) + rloc];
            float s = 0.f;
#pragma unroll
            for (int ni = 0; ni < 4; ++ni) {
                float x = acc[mi][ni][j] + Dco[ni] + av * w3o[ni];
                x = fminf(fmaxf(x, -15.f), 15.f);
                float e = __expf(2.f * x);
                s += ((e - 1.f) / (e + 1.f)) * tv[ni];
            }
#pragma unroll
            for (int off2 = 1; off2 < 16; off2 <<= 1) s += __shfl_xor(s, off2);
            if (l15 == 0) red[(rloc << 2) + wc] = s;
        }
    }
    __syncthreads();
    if (tid < 256) {
        partial[(size_t)((rb << 8) + tid) * 8 + cb] =
            red[(tid << 2)] + red[(tid << 2) + 1] + red[(tid << 2) + 2] + red[(tid << 2) + 3];
    }
}

// ---------- q softmax + q_context (merged; softmax recomputed per block) ----------
__global__ __launch_bounds__(256) void qctx_kernel(
    const float* __restrict__ partial_q, const int* __restrict__ q_mask,
    const float* __restrict__ q_value,
    float* __restrict__ out_qalphas, float* __restrict__ qctx) {
    int b = blockIdx.x, dc = blockIdx.y, tid = threadIdx.x;
    __shared__ float sal[64];
    if (tid < 64) {
        float s = 0.f;
        const float* p = partial_q + (size_t)(b * 64 + tid) * NCB;
#pragma unroll
        for (int c = 0; c < 16; c++) s += p[c];
        if (q_mask[b * 64 + tid] == 0) s = -INFINITY;
        float m = s;
        for (int off = 1; off < 64; off <<= 1) m = fmaxf(m, __shfl_xor(m, off));
        float e = (s == -INFINITY) ? 0.f : __expf(s - m);
        float sum = e;
        for (int off = 1; off < 64; off <<= 1) sum += __shfl_xor(sum, off);
        float a = e / sum;
        sal[tid] = a;
        if (dc == 0) out_qalphas[b * 64 + tid] = a;
    }
    __syncthreads();
    int d = (dc << 8) + tid;
    float acc = 0.f;
    for (int l = 0; l < 64; l++) {
        float al = sal[l];
        if (al != 0.f) acc += al * q_value[((size_t)(b * 64 + l) << 11) + d];
    }
    qctx[(b << 11) + d] = acc;
}

// ---------- text softmax over compacted scores: scatter + compacted output ----------
__global__ __launch_bounds__(256) void softmax_t_kernel(
    const float* __restrict__ partial,
    const int* __restrict__ idx, const int* __restrict__ cnt,
    float* __restrict__ out_alphas, float* __restrict__ alphas_c) {
    int b = blockIdx.x, tid = threadIdx.x;
    int wave = tid >> 6, lane = tid & 63;
    int cnt_b = cnt[b];
    __shared__ float sred[4];
    // zero-fill (masked positions stay 0)
#pragma unroll
    for (int i = 0; i < 8; i++) out_alphas[(b << 11) + tid + (i << 8)] = 0.f;
    __syncthreads();
    float sc[8];
    float lm = -INFINITY;
#pragma unroll
    for (int i = 0; i < 8; i++) {
        int j = tid + (i << 8);
        float s = -INFINITY;
        if (j < cnt_b) {
            const float* p = partial + (size_t)((b << 11) + j) * 8;
            s = 0.f;
#pragma unroll
            for (int c = 0; c < 8; c++) s += p[c];
        }
        sc[i] = s;
        lm = fmaxf(lm, s);
    }
    for (int off = 1; off < 64; off <<= 1) lm = fmaxf(lm, __shfl_xor(lm, off));
    if (lane == 0) sred[wave] = lm;
    __syncthreads();
    float m = fmaxf(fmaxf(sred[0], sred[1]), fmaxf(sred[2], sred[3]));
    float ee[8];
    float ls = 0.f;
#pragma unroll
    for (int i = 0; i < 8; i++) {
        ee[i] = (sc[i] == -INFINITY) ? 0.f : __expf(sc[i] - m);
        ls += ee[i];
    }
    for (int off = 1; off < 64; off <<= 1) ls += __shfl_xor(ls, off);
    __syncthreads();
    if (lane == 0) sred[wave] = ls;
    __syncthreads();
    float S = sred[0] + sred[1] + sred[2] + sred[3];
    float inv = 1.f / S;
#pragma unroll
    for (int i = 0; i < 8; i++) {
        int j = tid + (i << 8);
        float a = ee[i] * inv;
        alphas_c[(b << 11) + j] = (j < cnt_b) ? a : 0.f;
        if (j < cnt_b)
            out_alphas[(b << 11) + idx[(b << 11) + j]] = a;
    }
}

// ---------- context = alphas_c @ value[idx] (compacted gather, early exit) ----------
__global__ __launch_bounds__(256) void ctx_partial_kernel(
    const float* __restrict__ alphas_c,
    const int* __restrict__ idx, const int* __restrict__ cnt,
    const float* __restrict__ value,
    float* __restrict__ pctx) {
    int b = blockIdx.x, lc = blockIdx.y, tid = threadIdx.x;  // lc in [0,32)
    int cnt_b = cnt[b];
    if ((lc << 6) >= cnt_b) return;         // fully-padded slice: never read downstream
    __shared__ float sa[64];
    __shared__ int sidx[64];
    if (tid < 64) {
        int j = (lc << 6) + tid;
        sa[tid] = (j < cnt_b) ? alphas_c[(b << 11) + j] : 0.f;
        sidx[tid] = (j < cnt_b) ? idx[(b << 11) + j] : 0;
    }
    __syncthreads();
    f4v a0 = (f4v)0.f, a1 = (f4v)0.f;
    const float* vb = value + ((size_t)(b << 11) << 11);
    for (int l = 0; l < 64; l++) {
        float al = sa[l];
        if (al != 0.f) {
            const f4v* vr = (const f4v*)(vb + ((size_t)sidx[l] << 11));
            a0 += al * vr[tid];
            a1 += al * vr[tid + 256];
        }
    }
    f4v* p = (f4v*)(pctx + ((size_t)((b << 5) + lc) << 11));
    p[tid] = a0;
    p[tid + 256] = a1;
}

__global__ __launch_bounds__(256) void ctx_reduce_kernel(
    const float* __restrict__ pctx, const int* __restrict__ cnt,
    float* __restrict__ out_ctx) {
    int b = blockIdx.x, half = blockIdx.y, tid = threadIdx.x;
    int nlc = (cnt[b] + 63) >> 6;           // only slices actually written
    int d4 = (half << 8) + tid;
    f4v s = (f4v)0.f;
    for (int lc = 0; lc < nlc; lc++)
        s += ((const f4v*)(pctx + ((size_t)((b << 5) + lc) << 11)))[d4];
    ((f4v*)(out_ctx + ((size_t)b << 11)))[d4] = s;
}

// ---------- losses ----------
__global__ void loss_part_kernel(const float* __restrict__ qs, const float* __restrict__ qa,
                                 const float* __restrict__ ts, const float* __restrict__ ta,
                                 float* __restrict__ parts) {
    int blk = blockIdx.x, tid = threadIdx.x;  // 128 threads
    int wave = tid >> 6, lane = tid & 63;
    __shared__ float sred[2];
    float s = 0.f;
    if (blk == 0) {
        if (tid < 64) {
            float m = INFINITY;
#pragma unroll
            for (int b = 0; b < 16; ++b) {
                m = fminf(m, qs[(b << 6) + tid]);
                m = fminf(m, qa[(b << 6) + tid]);
            }
            s = m;
        }
    } else {
        int l = ((blk - 1) << 7) + tid;
        float m = INFINITY;
#pragma unroll
        for (int b = 0; b < 16; ++b) {
            m = fminf(m, ts[(b << 11) + l]);
            m = fminf(m, ta[(b << 11) + l]);
        }
        s = m;
    }
    for (int off = 1; off < 64; off <<= 1) s += __shfl_xor(s, off);
    if (lane == 0) sred[wave] = s;
    __syncthreads();
    if (tid == 0) parts[blk] = sred[0] + sred[1];
}

__global__ void loss_final_kernel(const float* __restrict__ parts,
                                  float* __restrict__ out_tl, float* __restrict__ out_ql) {
    if (threadIdx.x == 0) {
        *out_ql = parts[0];
        float t = 0.f;
        for (int i = 1; i <= 16; ++i) t += parts[i];
        *out_tl = t;
    }
}

extern "C" void kernel_launch(void* const* d_in, const int* in_sizes, int n_in,
                              void* d_out, int out_size, void* d_ws, size_t ws_size,
                              hipStream_t stream) {
    const float* query          = (const float*)d_in[0];
    const float* key            = (const float*)d_in[1];
    const float* value          = (const float*)d_in[2];
    const int*   mask           = (const int*)d_in[3];
    const float* q_key          = (const float*)d_in[4];
    const float* q_value        = (const float*)d_in[5];
    const int*   q_mask         = (const int*)d_in[6];
    const float* alphas_state   = (const float*)d_in[7];
    const float* q_alphas_state = (const float*)d_in[8];
    const float* W_q            = (const float*)d_in[9];
    const float* b_q            = (const float*)d_in[10];
    const float* W_t            = (const float*)d_in[11];
    const float* b_t            = (const float*)d_in[12];
    const float* query_other    = (const float*)d_in[13];
    const float* text_other     = (const float*)d_in[14];

    float* out        = (float*)d_out;
    float* out_ctx     = out;            // 16*2048
    float* out_alphas  = out + 32768;    // 16*2048
    float* out_qalphas = out + 65536;    // 16*64
    float* out_tloss   = out + 66560;
    float* out_qloss   = out + 66561;

    char* w = (char*)d_ws;
    size_t off = 0;
    auto alloc = [&](size_t bytes) -> char* {
        char* p = w + off;
        off += (bytes + 255) & ~(size_t)255;
        return p;
    };
    unsigned short* Wtk  = (unsigned short*)alloc(2048ull * 2048 * 2);
    unsigned short* Wqk  = (unsigned short*)alloc(2048ull * 2048 * 2);
    unsigned short* qkb  = (unsigned short*)alloc(1024ull * 2048 * 2);
    unsigned short* keyb = (unsigned short*)alloc(32768ull * 2048 * 2);
    float* partial_t     = (float*)alloc(32768ull * 8 * 4);
    float* partial_q     = (float*)alloc(1024ull * NCB * 4);
    float* Dq            = (float*)alloc(16 * 2048 * 4);
    float* Dt            = (float*)alloc(16 * 2048 * 4);
    float* qctx          = (float*)alloc(16 * 2048 * 4);
    float* w3q           = (float*)alloc(2048 * 4);
    float* w3t           = (float*)alloc(2048 * 4);
    float* pctx          = (float*)alloc(16ull * 32 * 2048 * 4);
    float* lparts        = (float*)alloc(32 * 4);
    int*   idx           = (int*)alloc(32768 * 4);
    int*   cnt           = (int*)alloc(64 * 4);
    float* avec_c        = (float*)alloc(32768 * 4);
    float* alphas_c      = (float*)alloc(32768 * 4);

    hipFuncSetAttribute((const void*)gemm256,
                        hipFuncAttributeMaxDynamicSharedMemorySize, 135168);

    // mask compaction, then merged conversions (gathered key + weights + q_key + w3 + Dq)
    mask_scan_kernel<<<16, 256, 0, stream>>>(mask, idx, cnt);
    prep_kernel<<<38408, 256, 0, stream>>>(W_t, W_q, q_key, key, query, b_q,
                                           alphas_state, idx, cnt,
                                           Wtk, Wqk, qkb, keyb, avec_c, w3q, w3t, Dq);

    // query-side GEMM + fused softmax+context
    gemm_score<6><<<128, 256, 0, stream>>>(qkb, Wqk, Dq, q_alphas_state, w3q,
                                           query_other, partial_q, 0);
    qctx_kernel<<<dim3(16, 8), 256, 0, stream>>>(partial_q, q_mask, q_value,
                                                 out_qalphas, qctx);

    // text-side constants, then bf16 GEMM over compacted rows
    dconst_kernel<3072><<<512, 256, 0, stream>>>(W_t, 5121, b_t, query, qctx, Dt);
    gemm256<<<1024, 512, 135168, stream>>>(keyb, Wtk, Dt, avec_c, w3t,
                                           text_other, cnt, partial_t);

    softmax_t_kernel<<<16, 256, 0, stream>>>(partial_t, idx, cnt, out_alphas, alphas_c);
    ctx_partial_kernel<<<dim3(16, 32), 256, 0, stream>>>(alphas_c, idx, cnt, value, pctx);
    ctx_reduce_kernel<<<dim3(16, 2), 256, 0, stream>>>(pctx, cnt, out_ctx);
    loss_part_kernel<<<17, 128, 0, stream>>>(q_alphas_state, out_qalphas,
                                             alphas_state, out_alphas, lparts);
    loss_final_kernel<<<1, 64, 0, stream>>>(lparts, out_tloss, out_qloss);
}

// Round 17
// 389.876 us; speedup vs baseline: 1.0881x; 1.0881x over previous
//
#include <hip/hip_runtime.h>
#include <hip/hip_bf16.h>
#include <math.h>

#define GK 2048
#define NCB 16   // query-side partial stride

typedef __attribute__((ext_vector_type(8))) short bf16x8;
typedef __attribute__((ext_vector_type(4))) float f32x4;
typedef __attribute__((ext_vector_type(4))) float f4v;
typedef __attribute__((ext_vector_type(4))) unsigned short u16x4;
typedef __attribute__((ext_vector_type(8))) unsigned short u16x8;

__device__ __forceinline__ unsigned short f2bf(float x) {
    unsigned int u = __float_as_uint(x);
    u += 0x7fffu + ((u >> 16) & 1u);
    return (unsigned short)(u >> 16);
}

__device__ __forceinline__ void gl_lds16(const void* g, void* l) {
    __builtin_amdgcn_global_load_lds(
        (const __attribute__((address_space(1))) unsigned int*)g,
        (__attribute__((address_space(3))) unsigned int*)l, 16, 0, 0);
}

// ---------- per-batch mask compaction: idx[b][j] = l of j-th unmasked, cnt[b] ----------
__global__ void mask_scan_kernel(const int* __restrict__ mask,
                                 int* __restrict__ idx, int* __restrict__ cnt) {
    int b = blockIdx.x, tid = threadIdx.x;
    int wave = tid >> 6, lane = tid & 63;
    __shared__ int wsum[4];
    __shared__ int sbase;
    if (tid == 0) sbase = 0;
    __syncthreads();
    for (int c = 0; c < 8; ++c) {
        int l = (c << 8) + tid;
        int m = mask[(b << 11) + l];
        unsigned long long bal = __ballot(m != 0);
        int wpfx = __popcll(bal & ((1ull << lane) - 1ull));
        if (lane == 0) wsum[wave] = __popcll(bal);
        int rbase = sbase;
        __syncthreads();
        int woff = 0;
#pragma unroll
        for (int w2 = 0; w2 < 4; ++w2) if (w2 < wave) woff += wsum[w2];
        if (m) idx[(b << 11) + rbase + woff + wpfx] = l;
        int tot = wsum[0] + wsum[1] + wsum[2] + wsum[3];
        __syncthreads();
        if (tid == 0) sbase = rbase + tot;
        __syncthreads();
    }
    if (tid == 0) cnt[b] = sbase;
}

// ---------- merged prep: gather-cvt key (compacted), cvt W_t/W_q/q_key, w3, Dq ----------
__global__ void prep_kernel(const float* __restrict__ Wt, const float* __restrict__ Wq,
                            const float* __restrict__ q_key, const float* __restrict__ key,
                            const float* __restrict__ query, const float* __restrict__ b_q,
                            const float* __restrict__ alphas_state,
                            const int* __restrict__ idx, const int* __restrict__ cnt,
                            unsigned short* __restrict__ Wtk, unsigned short* __restrict__ Wqk,
                            unsigned short* __restrict__ qkb, unsigned short* __restrict__ keyb,
                            float* __restrict__ avec_c,
                            float* __restrict__ w3q, float* __restrict__ w3t,
                            float* __restrict__ Dq) {
    int b = blockIdx.x, tid = threadIdx.x;
    if (b < 32768) {                       // compacted key slot: batch bb, slot j
        int bb = b >> 11, j = b & 2047;
        int c_ = cnt[bb];
        int lim = (c_ + 255) & ~255;       // rows beyond tile boundary never read
        if (j >= lim) return;
        unsigned short* drow = keyb + ((long)b << 11);
        if (j < c_) {
            int l = idx[b];
            const float* srow = key + (((size_t)(bb << 11) + l) << 11);
            long i = (long)tid << 3;
            f4v a = *(const f4v*)(srow + i);
            f4v c = *(const f4v*)(srow + i + 4);
            u16x8 r;
            r[0] = f2bf(a[0]); r[1] = f2bf(a[1]); r[2] = f2bf(a[2]); r[3] = f2bf(a[3]);
            r[4] = f2bf(c[0]); r[5] = f2bf(c[1]); r[6] = f2bf(c[2]); r[7] = f2bf(c[3]);
            *(u16x8*)(drow + i) = r;
            if (tid == 0) avec_c[b] = alphas_state[(bb << 11) + l];
        } else {
            u16x8 z = (u16x8)(short)0;
            *(u16x8*)(drow + (tid << 3)) = z;
            if (tid == 0) avec_c[b] = 0.f;
        }
        return;
    }
    int b2 = b - 32768;
    if (b2 < 2048) {
        const float* s = Wt + (size_t)b2 * 5121;
        unsigned short* d = Wtk + (size_t)b2 * 2048;
#pragma unroll
        for (int k = 0; k < 8; k++) { int c = tid + (k << 8); d[c] = f2bf(s[c]); }
    } else if (b2 < 4096) {
        int o = b2 - 2048;
        const float* s = Wq + (size_t)o * 3073;
        unsigned short* d = Wqk + (size_t)o * 2048;
#pragma unroll
        for (int k = 0; k < 8; k++) { int c = tid + (k << 8); d[c] = f2bf(s[c]); }
    } else if (b2 < 5120) {
        long i = ((long)(b2 - 4096) * 256 + tid) * 8;
        f4v a = *(const f4v*)(q_key + i);
        f4v c = *(const f4v*)(q_key + i + 4);
        u16x8 r;
        r[0] = f2bf(a[0]); r[1] = f2bf(a[1]); r[2] = f2bf(a[2]); r[3] = f2bf(a[3]);
        r[4] = f2bf(c[0]); r[5] = f2bf(c[1]); r[6] = f2bf(c[2]); r[7] = f2bf(c[3]);
        *(u16x8*)(qkb + i) = r;
    } else if (b2 < 5128) {
        int o = (b2 - 5120) * 256 + tid;
        w3q[o] = Wq[(size_t)o * 3073 + 3072];
        w3t[o] = Wt[(size_t)o * 5121 + 3072];
    } else {
        // Dq[bb][o] = b_q[o] + sum_i query[bb,i]*Wq[o,2048+i]
        int wave = tid >> 6, lane = tid & 63;
        int o = (b2 - 5128) * 4 + wave;
        const float* wrow = Wq + (size_t)o * 3073 + 2048;
        float acc[16];
#pragma unroll
        for (int z = 0; z < 16; z++) acc[z] = 0.f;
        for (int i = lane; i < 1024; i += 64) {
            float wv = wrow[i];
            const float* qp = query + i;
#pragma unroll
            for (int z = 0; z < 16; z++) acc[z] += wv * qp[z * 1024];
        }
#pragma unroll
        for (int z = 0; z < 16; z++) {
            float v = acc[z];
            for (int off = 1; off < 64; off <<= 1) v += __shfl_xor(v, off);
            if (lane == 0) Dq[(z << 11) + o] = v + b_q[o];
        }
    }
}

// ---------- per-batch constant D[b][o] (text side) ----------
template <int KLEN>
__global__ __launch_bounds__(256) void dconst_kernel(
    const float* __restrict__ W, long ldw,
    const float* __restrict__ bias,
    const float* __restrict__ query,
    const float* __restrict__ qctx,
    float* __restrict__ Dout) {
    int tid = threadIdx.x;
    int wave = tid >> 6, lane = tid & 63;
    int o = blockIdx.x * 4 + wave;
    const float* wrow = W + (size_t)o * ldw + 2048;
    float acc[16];
#pragma unroll
    for (int b2 = 0; b2 < 16; b2++) acc[b2] = 0.f;
    for (int i = lane; i < KLEN; i += 64) {
        if (KLEN == 1024 || i < 1024) {
            float wv = wrow[i];
            const float* qp = query + i;
#pragma unroll
            for (int b2 = 0; b2 < 16; b2++) acc[b2] += wv * qp[b2 * 1024];
        } else {
            float wv = wrow[i + 1];  // skip alphas column at 3072
            const float* cp = qctx + (i - 1024);
#pragma unroll
            for (int b2 = 0; b2 < 16; b2++) acc[b2] += wv * cp[b2 * 2048];
        }
    }
#pragma unroll
    for (int b2 = 0; b2 < 16; b2++) {
        float v = acc[b2];
        for (int off = 1; off < 64; off <<= 1) v += __shfl_xor(v, off);
        if (lane == 0) Dout[(b2 << 11) + o] = v + bias[o];
    }
}

// ---------- query-side fused GEMM (128x128 tile, m97 structure) ----------
template <int LOG_RPB>
__global__ __launch_bounds__(256) void gemm_score(
    const unsigned short* __restrict__ A,
    const unsigned short* __restrict__ Bt,
    const float* __restrict__ Dc,
    const float* __restrict__ avec,
    const float* __restrict__ w3,
    const float* __restrict__ tvec,
    float* __restrict__ partial,
    int row0) {
    __shared__ unsigned short As[128 * 32];
    __shared__ unsigned short Bs[128 * 32];
    __shared__ float red[128][2];

    int nwg = gridDim.x;
    int bid = blockIdx.x;
    int q8 = nwg >> 3;
    int wg = (bid & 7) * q8 + (bid >> 3);
    int rb = wg >> 4, cb = wg & 15;

    int tid = threadIdx.x;
    int wave = tid >> 6, lane = tid & 63;
    int wr = wave >> 1, wc = wave & 1;
    int l15 = lane & 15, lhi = lane >> 4;

    const unsigned short* Ab = A + (size_t)rb * 128 * GK;
    const unsigned short* Bb = Bt + (size_t)cb * 128 * GK;

    int r0 = tid >> 2, c0 = (tid & 3) << 3;

    f32x4 acc[4][4];
#pragma unroll
    for (int i = 0; i < 4; i++)
#pragma unroll
        for (int j = 0; j < 4; j++) acc[i][j] = (f32x4)0.f;

    unsigned short* AsW0 = As + (wave << 9);
    unsigned short* AsW1 = As + 2048 + (wave << 9);
    unsigned short* BsW0 = Bs + (wave << 9);
    unsigned short* BsW1 = Bs + 2048 + (wave << 9);

    for (int k0 = 0; k0 < GK; k0 += 32) {
        __syncthreads();
        gl_lds16(Ab + (size_t)r0 * GK + k0 + c0, AsW0);
        gl_lds16(Ab + (size_t)(r0 + 64) * GK + k0 + c0, AsW1);
        gl_lds16(Bb + (size_t)r0 * GK + k0 + c0, BsW0);
        gl_lds16(Bb + (size_t)(r0 + 64) * GK + k0 + c0, BsW1);
        __syncthreads();
        bf16x8 a[4], b[4];
#pragma unroll
        for (int mi = 0; mi < 4; mi++)
            a[mi] = *(const bf16x8*)(As + (((wr << 6) + (mi << 4) + l15) << 5) + (lhi << 3));
#pragma unroll
        for (int ni = 0; ni < 4; ni++)
            b[ni] = *(const bf16x8*)(Bs + (((wc << 6) + (ni << 4) + l15) << 5) + (lhi << 3));
#pragma unroll
        for (int mi = 0; mi < 4; mi++)
#pragma unroll
            for (int ni = 0; ni < 4; ni++)
                acc[mi][ni] = __builtin_amdgcn_mfma_f32_16x16x32_bf16(a[mi], b[ni], acc[mi][ni], 0, 0, 0);
    }

    int grow_base = row0 + (rb << 7) + (wr << 6);
    int bb = grow_base >> LOG_RPB;
    int gcol = (cb << 7) + (wc << 6) + l15;
    float Dco[4], w3o[4], tv[4];
#pragma unroll
    for (int ni = 0; ni < 4; ni++) {
        int o = gcol + (ni << 4);
        Dco[ni] = Dc[(bb << 11) + o];
        w3o[ni] = w3[o];
        tv[ni] = tvec[o];
    }
#pragma unroll
    for (int mi = 0; mi < 4; mi++) {
#pragma unroll
        for (int j = 0; j < 4; j++) {
            int rloc = (mi << 4) + (lhi << 2) + j;
            float av = avec[grow_base + rloc];
            float s = 0.f;
#pragma unroll
            for (int ni = 0; ni < 4; ni++) {
                float x = acc[mi][ni][j] + Dco[ni] + av * w3o[ni];
                x = fminf(fmaxf(x, -15.f), 15.f);
                float e = __expf(2.f * x);
                s += ((e - 1.f) / (e + 1.f)) * tv[ni];
            }
#pragma unroll
            for (int off = 1; off < 16; off <<= 1) s += __shfl_xor(s, off);
            if (l15 == 0) red[(wr << 6) + rloc][wc] = s;
        }
    }
    __syncthreads();
    if (tid < 128) {
        partial[(size_t)(row0 + (rb << 7) + tid) * NCB + cb] = red[tid][0] + red[tid][1];
    }
}

// ---------- text-side 256x256 8-phase GEMM (r10 structure) + mask-compaction exit ----
#define MFMA16(A, B, C) __builtin_amdgcn_mfma_f32_16x16x32_bf16(A, B, C, 0, 0, 0)

#define STAGE2(GB, GR0, K0, LB) do { \
    int _rr = lane >> 3; \
    int _cc = ((lane & 7) ^ _rr) << 3; \
    gl_lds16((GB) + (size_t)((GR0) + (wid << 3) + _rr) * GK + (K0) + _cc, lds + (LB) + (wid << 9)); \
    gl_lds16((GB) + (size_t)((GR0) + 64 + (wid << 3) + _rr) * GK + (K0) + _cc, lds + (LB) + 4096 + (wid << 9)); \
  } while (0)

#define WAIT4 do { asm volatile("s_waitcnt vmcnt(4)" ::: "memory"); __builtin_amdgcn_sched_barrier(0); } while (0)
#define NOWAIT do { } while (0)

#define PHASE(YOFF, Q, FIRSTB, STAGE_STMT, BOUNDARY) do { \
    bf16x8 a00, a01, a10, a11; \
    if (FIRSTB) { \
        b00 = *(const bf16x8*)(lds8 + bB0[0] + (YOFF)); b01 = *(const bf16x8*)(lds8 + bB1[0] + (YOFF)); \
        b10 = *(const bf16x8*)(lds8 + bB0[1] + (YOFF)); b11 = *(const bf16x8*)(lds8 + bB1[1] + (YOFF)); \
        b20 = *(const bf16x8*)(lds8 + bB0[2] + (YOFF)); b21 = *(const bf16x8*)(lds8 + bB1[2] + (YOFF)); \
        b30 = *(const bf16x8*)(lds8 + bB0[3] + (YOFF)); b31 = *(const bf16x8*)(lds8 + bB1[3] + (YOFF)); \
    } \
    a00 = *(const bf16x8*)(lds8 + aA0[2*(Q)  ] + (YOFF)); a01 = *(const bf16x8*)(lds8 + aA1[2*(Q)  ] + (YOFF)); \
    a10 = *(const bf16x8*)(lds8 + aA0[2*(Q)+1] + (YOFF)); a11 = *(const bf16x8*)(lds8 + aA1[2*(Q)+1] + (YOFF)); \
    STAGE_STMT; \
    BOUNDARY; \
    __builtin_amdgcn_s_barrier(); \
    asm volatile("s_waitcnt lgkmcnt(0)" ::: "memory"); \
    __builtin_amdgcn_sched_barrier(0); \
    __builtin_amdgcn_s_setprio(1); \
    acc[2*(Q)  ][0] = MFMA16(a00, b00, acc[2*(Q)  ][0]); \
    acc[2*(Q)  ][0] = MFMA16(a01, b01, acc[2*(Q)  ][0]); \
    acc[2*(Q)  ][1] = MFMA16(a00, b10, acc[2*(Q)  ][1]); \
    acc[2*(Q)  ][1] = MFMA16(a01, b11, acc[2*(Q)  ][1]); \
    acc[2*(Q)  ][2] = MFMA16(a00, b20, acc[2*(Q)  ][2]); \
    acc[2*(Q)  ][2] = MFMA16(a01, b21, acc[2*(Q)  ][2]); \
    acc[2*(Q)  ][3] = MFMA16(a00, b30, acc[2*(Q)  ][3]); \
    acc[2*(Q)  ][3] = MFMA16(a01, b31, acc[2*(Q)  ][3]); \
    acc[2*(Q)+1][0] = MFMA16(a10, b00, acc[2*(Q)+1][0]); \
    acc[2*(Q)+1][0] = MFMA16(a11, b01, acc[2*(Q)+1][0]); \
    acc[2*(Q)+1][1] = MFMA16(a10, b10, acc[2*(Q)+1][1]); \
    acc[2*(Q)+1][1] = MFMA16(a11, b11, acc[2*(Q)+1][1]); \
    acc[2*(Q)+1][2] = MFMA16(a10, b20, acc[2*(Q)+1][2]); \
    acc[2*(Q)+1][2] = MFMA16(a11, b21, acc[2*(Q)+1][2]); \
    acc[2*(Q)+1][3] = MFMA16(a10, b30, acc[2*(Q)+1][3]); \
    acc[2*(Q)+1][3] = MFMA16(a11, b31, acc[2*(Q)+1][3]); \
    __builtin_amdgcn_s_setprio(0); \
  } while (0)

__global__ __launch_bounds__(512, 2) void gemm256(
    const unsigned short* __restrict__ A,
    const unsigned short* __restrict__ Bt,
    const float* __restrict__ Dc,
    const float* __restrict__ avec,
    const float* __restrict__ w3,
    const float* __restrict__ tvec,
    const int* __restrict__ cnt,
    float* __restrict__ partial) {
    extern __shared__ unsigned short lds[];
    char* lds8 = (char*)lds;
    const int XA = 0, YA = 16384, XB = 32768, YB = 49152;  // ushort units

    int nwg = gridDim.x;
    int bid = blockIdx.x;
    int q8 = nwg >> 3;
    int wg = (bid & 7) * q8 + (bid >> 3);   // bijective XCD swizzle (nwg % 8 == 0)
    int rb = wg >> 3, cb = wg & 7;

    // mask-compaction early exit: this 256-row tile is entirely padding
    if (((rb & 7) << 8) >= cnt[rb >> 3]) return;

    int tid = threadIdx.x;
    int wid = tid >> 6, lane = tid & 63;
    int wr = wid >> 2, wc = wid & 3;
    int l15 = lane & 15, lhi = lane >> 4;

    const unsigned short* Aq = A;
    const unsigned short* Bq = Bt;
    int arow = rb << 8;
    int brow = cb << 8;

    // hoisted LDS read addresses (bytes, X-group base; Y-group = +32768)
    int sw0 = ((lhi ^ (l15 & 7)) << 4);
    int sw1 = (((4 | lhi) ^ (l15 & 7)) << 4);
    int aA0[8], aA1[8], bB0[4], bB1[4];
#pragma unroll
    for (int mi = 0; mi < 8; mi++) {
        int r = (wr << 7) + (mi << 4) + l15;
        aA0[mi] = (r << 7) + sw0;
        aA1[mi] = (r << 7) + sw1;
    }
#pragma unroll
    for (int ni = 0; ni < 4; ni++) {
        int r = (wc << 6) + (ni << 4) + l15;
        bB0[ni] = 65536 + (r << 7) + sw0;
        bB1[ni] = 65536 + (r << 7) + sw1;
    }

    f32x4 acc[8][4];
#pragma unroll
    for (int i = 0; i < 8; i++)
#pragma unroll
        for (int j = 0; j < 4; j++) acc[i][j] = (f32x4)0.f;

    bf16x8 b00, b01, b10, b11, b20, b21, b30, b31;

    // prologue: X <- tile0 (B then A), Y.B <- tile1
    STAGE2(Bq, brow, 0, XB);
    STAGE2(Bq, brow + 128, 0, XB + 8192);
    STAGE2(Aq, arow, 0, XA);
    STAGE2(Aq, arow + 128, 0, XA + 8192);
    STAGE2(Bq, brow, 64, YB);
    STAGE2(Bq, brow + 128, 64, YB + 8192);
    asm volatile("s_waitcnt vmcnt(4)" ::: "memory");
    __builtin_amdgcn_sched_barrier(0);
    __builtin_amdgcn_s_barrier();

    for (int it = 0; it < 16; ++it) {
        int k1 = ((it << 1) + 1) << 6;           // tile 2i+1 A (real)
        int k2 = (((it << 1) + 2) << 6) & 2047;  // tile 2i+2 (masked harmless on last iter)
        int k3 = (((it << 1) + 3) << 6) & 2047;  // tile 2i+3
        PHASE(0,     0, 1, STAGE2(Aq, arow,       k1, YA),        NOWAIT);
        PHASE(0,     1, 0, STAGE2(Aq, arow + 128, k1, YA + 8192), NOWAIT);
        PHASE(0,     2, 0, STAGE2(Bq, brow,       k2, XB),        NOWAIT);
        PHASE(0,     3, 0, STAGE2(Bq, brow + 128, k2, XB + 8192), WAIT4);
        PHASE(32768, 0, 1, STAGE2(Aq, arow,       k2, XA),        NOWAIT);
        PHASE(32768, 1, 0, STAGE2(Aq, arow + 128, k2, XA + 8192), NOWAIT);
        PHASE(32768, 2, 0, STAGE2(Bq, brow,       k3, YB),        NOWAIT);
        PHASE(32768, 3, 0, STAGE2(Bq, brow + 128, k3, YB + 8192), WAIT4);
    }

    // epilogue: fused tanh-dot partial scores (compacted rows)
    int gcolb = (cb << 8) + (wc << 6) + l15;
    int bb = rb >> 3;
    float Dco[4], w3o[4], tv[4];
#pragma unroll
    for (int ni = 0; ni < 4; ++ni) {
        int o = gcolb + (ni << 4);
        Dco[ni] = Dc[(bb << 11) + o];
        w3o[ni] = w3[o];
        tv[ni] = tvec[o];
    }
    float* red = (float*)(lds + 65536);  // [256][4]
#pragma unroll
    for (int mi = 0; mi < 8; ++mi) {
#pragma unroll
        for (int j = 0; j < 4; ++j) {
            int rloc = (wr << 7) + (mi << 4) + (lhi << 2) + j;
            float av = avec[(rb << 8) + rloc];
            float s = 0.f;
#pragma unroll
            for (int ni = 0; ni < 4; ++ni) {
                float x = acc[mi][ni][j] + Dco[ni] + av * w3o[ni];
                x = fminf(fmaxf(x, -15.f), 15.f);
                float e = __expf(2.f * x);
                s += ((e - 1.f) / (e + 1.f)) * tv[ni];
            }
#pragma unroll
            for (int off2 = 1; off2 < 16; off2 <<= 1) s += __shfl_xor(s, off2);
            if (l15 == 0) red[(rloc << 2) + wc] = s;
        }
    }
    __syncthreads();
    if (tid < 256) {
        partial[(size_t)((rb << 8) + tid) * 8 + cb] =
            red[(tid << 2)] + red[(tid << 2) + 1] + red[(tid << 2) + 2] + red[(tid << 2) + 3];
    }
}

// ---------- q softmax + q_context (merged; softmax recomputed per block) ----------
__global__ __launch_bounds__(256) void qctx_kernel(
    const float* __restrict__ partial_q, const int* __restrict__ q_mask,
    const float* __restrict__ q_value,
    float* __restrict__ out_qalphas, float* __restrict__ qctx) {
    int b = blockIdx.x, dc = blockIdx.y, tid = threadIdx.x;
    __shared__ float sal[64];
    if (tid < 64) {
        float s = 0.f;
        const float* p = partial_q + (size_t)(b * 64 + tid) * NCB;
#pragma unroll
        for (int c = 0; c < 16; c++) s += p[c];
        if (q_mask[b * 64 + tid] == 0) s = -INFINITY;
        float m = s;
        for (int off = 1; off < 64; off <<= 1) m = fmaxf(m, __shfl_xor(m, off));
        float e = (s == -INFINITY) ? 0.f : __expf(s - m);
        float sum = e;
        for (int off = 1; off < 64; off <<= 1) sum += __shfl_xor(sum, off);
        float a = e / sum;
        sal[tid] = a;
        if (dc == 0) out_qalphas[b * 64 + tid] = a;
    }
    __syncthreads();
    int d = (dc << 8) + tid;
    float acc = 0.f;
    for (int l = 0; l < 64; l++) {
        float al = sal[l];
        if (al != 0.f) acc += al * q_value[((size_t)(b * 64 + l) << 11) + d];
    }
    qctx[(b << 11) + d] = acc;
}

// ---------- text softmax over compacted scores, scatter to original positions ----------
__global__ __launch_bounds__(256) void softmax_t_kernel(
    const float* __restrict__ partial,
    const int* __restrict__ idx, const int* __restrict__ cnt,
    float* __restrict__ out_alphas) {
    int b = blockIdx.x, tid = threadIdx.x;
    int wave = tid >> 6, lane = tid & 63;
    int cnt_b = cnt[b];
    __shared__ float sred[4];
    // zero-fill (masked positions stay 0)
#pragma unroll
    for (int i = 0; i < 8; i++) out_alphas[(b << 11) + tid + (i << 8)] = 0.f;
    __syncthreads();
    float sc[8];
    float lm = -INFINITY;
#pragma unroll
    for (int i = 0; i < 8; i++) {
        int j = tid + (i << 8);
        const float* p = partial + (size_t)((b << 11) + j) * 8;
        float s = 0.f;
#pragma unroll
        for (int c = 0; c < 8; c++) s += p[c];
        if (j >= cnt_b) s = -INFINITY;
        sc[i] = s;
        lm = fmaxf(lm, s);
    }
    for (int off = 1; off < 64; off <<= 1) lm = fmaxf(lm, __shfl_xor(lm, off));
    if (lane == 0) sred[wave] = lm;
    __syncthreads();
    float m = fmaxf(fmaxf(sred[0], sred[1]), fmaxf(sred[2], sred[3]));
    float ee[8];
    float ls = 0.f;
#pragma unroll
    for (int i = 0; i < 8; i++) {
        ee[i] = (sc[i] == -INFINITY) ? 0.f : __expf(sc[i] - m);
        ls += ee[i];
    }
    for (int off = 1; off < 64; off <<= 1) ls += __shfl_xor(ls, off);
    __syncthreads();
    if (lane == 0) sred[wave] = ls;
    __syncthreads();
    float S = sred[0] + sred[1] + sred[2] + sred[3];
    float inv = 1.f / S;
#pragma unroll
    for (int i = 0; i < 8; i++) {
        int j = tid + (i << 8);
        if (j < cnt_b)
            out_alphas[(b << 11) + idx[(b << 11) + j]] = ee[i] * inv;
    }
}

// ---------- context = alphas @ value (512 blocks) ----------
__global__ __launch_bounds__(256) void ctx_partial_kernel(
    const float* __restrict__ alphas,
    const float* __restrict__ value,
    float* __restrict__ pctx) {
    int b = blockIdx.x, lc = blockIdx.y, tid = threadIdx.x;  // lc in [0,32)
    __shared__ float sa[64];
    if (tid < 64) sa[tid] = alphas[(b << 11) + (lc << 6) + tid];
    __syncthreads();
    f4v a0 = (f4v)0.f, a1 = (f4v)0.f;
    const float* vb = value + ((size_t)((b << 11) + (lc << 6)) << 11);
    for (int l = 0; l < 64; l++) {
        float al = sa[l];
        if (al != 0.f) {  // masked rows skipped (alpha exactly 0)
            const f4v* vr = (const f4v*)(vb + ((size_t)l << 11));
            a0 += al * vr[tid];
            a1 += al * vr[tid + 256];
        }
    }
    f4v* p = (f4v*)(pctx + ((size_t)((b << 5) + lc) << 11));
    p[tid] = a0;
    p[tid + 256] = a1;
}

__global__ __launch_bounds__(256) void ctx_reduce_kernel(
    const float* __restrict__ pctx, float* __restrict__ out_ctx) {
    int b = blockIdx.x, half = blockIdx.y, tid = threadIdx.x;
    int d4 = (half << 8) + tid;
    f4v s = (f4v)0.f;
#pragma unroll
    for (int lc = 0; lc < 32; lc++)
        s += ((const f4v*)(pctx + ((size_t)((b << 5) + lc) << 11)))[d4];
    ((f4v*)(out_ctx + ((size_t)b << 11)))[d4] = s;
}

// ---------- losses ----------
__global__ void loss_part_kernel(const float* __restrict__ qs, const float* __restrict__ qa,
                                 const float* __restrict__ ts, const float* __restrict__ ta,
                                 float* __restrict__ parts) {
    int blk = blockIdx.x, tid = threadIdx.x;  // 128 threads
    int wave = tid >> 6, lane = tid & 63;
    __shared__ float sred[2];
    float s = 0.f;
    if (blk == 0) {
        if (tid < 64) {
            float m = INFINITY;
#pragma unroll
            for (int b = 0; b < 16; ++b) {
                m = fminf(m, qs[(b << 6) + tid]);
                m = fminf(m, qa[(b << 6) + tid]);
            }
            s = m;
        }
    } else {
        int l = ((blk - 1) << 7) + tid;
        float m = INFINITY;
#pragma unroll
        for (int b = 0; b < 16; ++b) {
            m = fminf(m, ts[(b << 11) + l]);
            m = fminf(m, ta[(b << 11) + l]);
        }
        s = m;
    }
    for (int off = 1; off < 64; off <<= 1) s += __shfl_xor(s, off);
    if (lane == 0) sred[wave] = s;
    __syncthreads();
    if (tid == 0) parts[blk] = sred[0] + sred[1];
}

__global__ void loss_final_kernel(const float* __restrict__ parts,
                                  float* __restrict__ out_tl, float* __restrict__ out_ql) {
    if (threadIdx.x == 0) {
        *out_ql = parts[0];
        float t = 0.f;
        for (int i = 1; i <= 16; ++i) t += parts[i];
        *out_tl = t;
    }
}

extern "C" void kernel_launch(void* const* d_in, const int* in_sizes, int n_in,
                              void* d_out, int out_size, void* d_ws, size_t ws_size,
                              hipStream_t stream) {
    const float* query          = (const float*)d_in[0];
    const float* key            = (const float*)d_in[1];
    const float* value          = (const float*)d_in[2];
    const int*   mask           = (const int*)d_in[3];
    const float* q_key          = (const float*)d_in[4];
    const float* q_value        = (const float*)d_in[5];
    const int*   q_mask         = (const int*)d_in[6];
    const float* alphas_state   = (const float*)d_in[7];
    const float* q_alphas_state = (const float*)d_in[8];
    const float* W_q            = (const float*)d_in[9];
    const float* b_q            = (const float*)d_in[10];
    const float* W_t            = (const float*)d_in[11];
    const float* b_t            = (const float*)d_in[12];
    const float* query_other    = (const float*)d_in[13];
    const float* text_other     = (const float*)d_in[14];

    float* out        = (float*)d_out;
    float* out_ctx     = out;            // 16*2048
    float* out_alphas  = out + 32768;    // 16*2048
    float* out_qalphas = out + 65536;    // 16*64
    float* out_tloss   = out + 66560;
    float* out_qloss   = out + 66561;

    char* w = (char*)d_ws;
    size_t off = 0;
    auto alloc = [&](size_t bytes) -> char* {
        char* p = w + off;
        off += (bytes + 255) & ~(size_t)255;
        return p;
    };
    unsigned short* Wtk  = (unsigned short*)alloc(2048ull * 2048 * 2);
    unsigned short* Wqk  = (unsigned short*)alloc(2048ull * 2048 * 2);
    unsigned short* qkb  = (unsigned short*)alloc(1024ull * 2048 * 2);
    unsigned short* keyb = (unsigned short*)alloc(32768ull * 2048 * 2);
    float* partial_t     = (float*)alloc(32768ull * 8 * 4);
    float* partial_q     = (float*)alloc(1024ull * NCB * 4);
    float* Dq            = (float*)alloc(16 * 2048 * 4);
    float* Dt            = (float*)alloc(16 * 2048 * 4);
    float* qctx          = (float*)alloc(16 * 2048 * 4);
    float* w3q           = (float*)alloc(2048 * 4);
    float* w3t           = (float*)alloc(2048 * 4);
    float* pctx          = (float*)alloc(16ull * 32 * 2048 * 4);
    float* lparts        = (float*)alloc(32 * 4);
    int*   idx           = (int*)alloc(32768 * 4);
    int*   cnt           = (int*)alloc(64 * 4);
    float* avec_c        = (float*)alloc(32768 * 4);

    hipFuncSetAttribute((const void*)gemm256,
                        hipFuncAttributeMaxDynamicSharedMemorySize, 135168);

    // mask compaction, then merged conversions (gathered key + weights + q_key + w3 + Dq)
    mask_scan_kernel<<<16, 256, 0, stream>>>(mask, idx, cnt);
    prep_kernel<<<38408, 256, 0, stream>>>(W_t, W_q, q_key, key, query, b_q,
                                           alphas_state, idx, cnt,
                                           Wtk, Wqk, qkb, keyb, avec_c, w3q, w3t, Dq);

    // query-side GEMM + fused softmax+context
    gemm_score<6><<<128, 256, 0, stream>>>(qkb, Wqk, Dq, q_alphas_state, w3q,
                                           query_other, partial_q, 0);
    qctx_kernel<<<dim3(16, 8), 256, 0, stream>>>(partial_q, q_mask, q_value,
                                                 out_qalphas, qctx);

    // text-side constants, then bf16 GEMM over compacted rows
    dconst_kernel<3072><<<512, 256, 0, stream>>>(W_t, 5121, b_t, query, qctx, Dt);
    gemm256<<<1024, 512, 135168, stream>>>(keyb, Wtk, Dt, avec_c, w3t,
                                           text_other, cnt, partial_t);

    softmax_t_kernel<<<16, 256, 0, stream>>>(partial_t, idx, cnt, out_alphas);
    ctx_partial_kernel<<<dim3(16, 32), 256, 0, stream>>>(out_alphas, value, pctx);
    ctx_reduce_kernel<<<dim3(16, 2), 256, 0, stream>>>(pctx, out_ctx);
    loss_part_kernel<<<17, 128, 0, stream>>>(q_alphas_state, out_qalphas,
                                             alphas_state, out_alphas, lparts);
    loss_final_kernel<<<1, 64, 0, stream>>>(lparts, out_tloss, out_qloss);
}